// Round 1
// baseline (155.854 us; speedup 1.0000x reference)
//
#include <hip/hip_runtime.h>
#include <math.h>

#define SDIM 376
#define ADIM 17
#define DIN  393
#define H1   400
#define H2   300
#define TSTEPS 32
#define KP 416   // 13*32 (padded DIN)
#define NKT 13   // K tiles of 32
#define NT2 19   // n-tiles for H2 (304 padded cols)
#define KP2 416  // padded H1 (K-dim of bound GEMM)

typedef __bf16 bf16x8 __attribute__((ext_vector_type(8)));
typedef float  f32x4  __attribute__((ext_vector_type(4)));

// Fragment-major layouts: frag for (tile, kt) is 64 lanes x 8 bf16, contiguous:
//   A_sw[((mtile*13 + kt)*64 + lane)*8 + e]   lane = quad*16 + (row&15), e = k&7, quad=(k>>3)&3
//   B_sw[((ntile*13 + kt)*64 + lane)*8 + e]   lane = quad*16 + (col&15)
// => every MFMA fragment load is ONE coalesced 1KB wave transaction.
//
// R0 experiment: replace snn_actor's serial W2+ gather (18 dependent L2 round-trips
// per row) with a bound-GEMM: mask(0/1 bf16) @ W2+(bf16 frags). Threshold 0.999->0.92
// covers worst-case bf16 under-count (<=400*1.95e-4=0.078); typical bound ~0.22.

// ---------- K0 (fused prep): input -> A_sw | W1 -> B_sw | W2+ -> B2_sw ----------
__global__ __launch_bounds__(256) void prep_fused(
    const float* __restrict__ state, const float* __restrict__ action,
    const float* __restrict__ W1, const float* __restrict__ W2,
    __bf16* __restrict__ A_sw, __bf16* __restrict__ B_sw, __bf16* __restrict__ B2_sw,
    int B, int npack, int nw1t) {
    const int bid = blockIdx.x, tid = threadIdx.x;
    if (bid < npack) {
        // pack concat(state,action,0): thread -> (row r, 8-col chunk c); source reads coalesced
        int idx = bid * 256 + tid;
        int r = idx / 52, c = idx - r * 52;
        if (r >= B) return;
        int g0 = c * 8;
        float v[8];
        if (g0 + 7 < SDIM) {
            float4 a = *(const float4*)&state[r * SDIM + g0];
            float4 b = *(const float4*)&state[r * SDIM + g0 + 4];
            v[0]=a.x; v[1]=a.y; v[2]=a.z; v[3]=a.w; v[4]=b.x; v[5]=b.y; v[6]=b.z; v[7]=b.w;
        } else {
            #pragma unroll
            for (int e = 0; e < 8; ++e) {
                int k = g0 + e;
                v[e] = (k < SDIM) ? state[r * SDIM + k]
                     : (k < DIN)  ? action[r * ADIM + k - SDIM] : 0.f;
            }
        }
        bf16x8 o;
        #pragma unroll
        for (int e = 0; e < 8; ++e) o[e] = (__bf16)v[e];
        int kt = g0 >> 5, quad = (g0 >> 3) & 3;
        *(bf16x8*)&A_sw[(((size_t)(r >> 4) * NKT + kt) * 64 + (quad << 4) + (r & 15)) * 8] = o;
    } else if (bid < npack + nw1t) {
        // W1 [k][n] -> B_sw, k-major thread mapping => W1 reads fully coalesced
        int idx = (bid - npack) * 256 + tid;
        if (idx >= H1 * KP) return;
        int k = idx / H1, n = idx - k * H1;
        float val = (k < DIN) ? W1[k * H1 + n] : 0.f;
        int ntile = n >> 4, kt = k >> 5, quad = (k >> 3) & 3;
        B_sw[(((size_t)ntile * NKT + kt) * 64 + (quad << 4) + (n & 15)) * 8 + (k & 7)] = (__bf16)val;
    } else {
        // W2+ = max(W2,0) [k2][n2] -> B2_sw frags, k2 in [0,416), n2 in [0,304)
        int idx = (bid - npack - nw1t) * 256 + tid;
        if (idx >= KP2 * 304) return;
        int k = idx / 304, n = idx - k * 304;
        float val = (k < H1 && n < H2) ? fmaxf(W2[k * H2 + n], 0.f) : 0.f;
        int ntile = n >> 4, kt = k >> 5, quad = (k >> 3) & 3;
        B2_sw[(((size_t)ntile * NKT + kt) * 64 + (quad << 4) + (n & 15)) * 8 + (k & 7)] = (__bf16)val;
    }
}

// ---------- K1: GEMM -> spike mask. Unchanged. ----------
__global__ __launch_bounds__(256) void gemm_mask(
    const __bf16* __restrict__ A_sw, const __bf16* __restrict__ B_sw,
    const float* __restrict__ b1, unsigned short* __restrict__ maskbuf) {
    const int tid = threadIdx.x, wave = tid >> 6, lane = tid & 63;
    const int quad = lane >> 4, l16 = lane & 15;
    const int mtile = blockIdx.x * 4 + wave;       // this wave's 16 rows
    const int bn0 = blockIdx.y * 80;               // 5 n-tiles

    f32x4 acc[5];
    #pragma unroll
    for (int n = 0; n < 5; ++n) acc[n] = (f32x4){0.f, 0.f, 0.f, 0.f};

    const __bf16* ap = A_sw + ((size_t)mtile * NKT * 64 + lane) * 8;
    const __bf16* bp = B_sw + ((size_t)(blockIdx.y * 5) * NKT * 64 + lane) * 8;

    #pragma unroll
    for (int kt = 0; kt < NKT; ++kt) {
        bf16x8 af = *(const bf16x8*)(ap + (size_t)kt * 512);
        #pragma unroll
        for (int n = 0; n < 5; ++n) {
            bf16x8 bfrag = *(const bf16x8*)(bp + ((size_t)n * NKT + kt) * 512);
            acc[n] = __builtin_amdgcn_mfma_f32_16x16x32_bf16(af, bfrag, acc[n], 0, 0, 0);
        }
    }

    float b1v[5];
    #pragma unroll
    for (int n = 0; n < 5; ++n) b1v[n] = b1[bn0 + n * 16 + l16];
    const int cbase = bn0 >> 4;  // chunk base = blockIdx.y*5
    const int bm0 = mtile * 16;
    #pragma unroll
    for (int n = 0; n < 5; ++n)
        #pragma unroll
        for (int reg = 0; reg < 4; ++reg) {
            // 0.99: superset of {x1_ref >= 1}; bf16 GEMM |err| << 0.01 at this K/scale
            unsigned long long bal = __ballot(acc[n][reg] + b1v[n] >= 0.99f);
            if (l16 == 0)
                maskbuf[(size_t)(bm0 + quad * 4 + reg) * 32 + cbase + n] =
                    (unsigned short)(bal >> (quad * 16));
        }
}

// ---------- K2': bound GEMM + epilogue. One wave per 32 rows (2 m-tiles).
// bound[j] = b2[j] + sum_{i in mask} bf16(max(W2[i][j],0)) via MFMA; if all j:
// bound < 0.92 => s2==0 => closed-form out. Tier-3 full sim kept as soundness net. ----------
__global__ __launch_bounds__(64) void bound_gemm(
    const unsigned long long* __restrict__ mask64,   // [B][8] (chunks 25..31 invalid)
    const __bf16* __restrict__ B2_sw,
    const float* __restrict__ state, const float* __restrict__ action,
    const float* __restrict__ W1, const float* __restrict__ b1,
    const float* __restrict__ W2, const float* __restrict__ b2,
    const float* __restrict__ W3, const float* __restrict__ b3,
    float* __restrict__ out) {
    const int lane = threadIdx.x;
    const int l16 = lane & 15, quad = lane >> 4;
    const int base = blockIdx.x * 32;

    // per-lane: mask words of this lane's A-fragment row for each of the 2 m-tiles
    unsigned long long mw0[7], mw1[7];
    #pragma unroll
    for (int w = 0; w < 7; ++w) {
        mw0[w] = mask64[(size_t)(base + l16) * 8 + w];
        mw1[w] = mask64[(size_t)(base + 16 + l16) * 8 + w];
    }
    mw0[6] &= 0xFFFFULL; mw1[6] &= 0xFFFFULL;  // chunks 25..27 are unwritten ws

    f32x4 acc0[NT2], acc1[NT2];
    #pragma unroll
    for (int n = 0; n < NT2; ++n) {
        acc0[n] = (f32x4){0.f, 0.f, 0.f, 0.f};
        acc1[n] = (f32x4){0.f, 0.f, 0.f, 0.f};
    }

    const __bf16* bp = B2_sw + (size_t)lane * 8;
    #pragma unroll
    for (int kt = 0; kt < NKT; ++kt) {
        // A-frag bits: k = kt*32 + quad*8 + e of row (base + mt*16 + l16)
        const int bit0 = ((kt & 1) << 5) | (quad << 3);
        unsigned by0 = (unsigned)(mw0[kt >> 1] >> bit0) & 0xFFu;
        unsigned by1 = (unsigned)(mw1[kt >> 1] >> bit0) & 0xFFu;
        bf16x8 a0, a1;
        #pragma unroll
        for (int e = 0; e < 8; ++e) {
            a0[e] = ((by0 >> e) & 1u) ? (__bf16)1.0f : (__bf16)0.0f;
            a1[e] = ((by1 >> e) & 1u) ? (__bf16)1.0f : (__bf16)0.0f;
        }
        #pragma unroll
        for (int n = 0; n < NT2; ++n) {
            bf16x8 bfrag = *(const bf16x8*)(bp + ((size_t)(n * NKT + kt) * 64) * 8);
            acc0[n] = __builtin_amdgcn_mfma_f32_16x16x32_bf16(a0, bfrag, acc0[n], 0, 0, 0);
            acc1[n] = __builtin_amdgcn_mfma_f32_16x16x32_bf16(a1, bfrag, acc1[n], 0, 0, 0);
        }
    }

    // epilogue: per-row OK = all 304 cols bound < 0.92 (pad cols give 0 < 0.92)
    float b2v[NT2];
    #pragma unroll
    for (int n = 0; n < NT2; ++n) {
        int j = n * 16 + l16;
        b2v[n] = (j < H2) ? b2[j] : 0.f;
    }
    unsigned rowok = 0;  // bits 0..31 <-> rows base..base+31 (wave-uniform)
    {
        bool okr[4] = {true, true, true, true};
        #pragma unroll
        for (int n = 0; n < NT2; ++n)
            #pragma unroll
            for (int reg = 0; reg < 4; ++reg)
                okr[reg] = okr[reg] && (acc0[n][reg] + b2v[n] < 0.92f);
        #pragma unroll
        for (int reg = 0; reg < 4; ++reg) {
            unsigned long long bal = __ballot(okr[reg]);
            #pragma unroll
            for (int q = 0; q < 4; ++q)
                if (((bal >> (q * 16)) & 0xFFFFULL) == 0xFFFFULL)
                    rowok |= 1u << (q * 4 + reg);
        }
    }
    {
        bool okr[4] = {true, true, true, true};
        #pragma unroll
        for (int n = 0; n < NT2; ++n)
            #pragma unroll
            for (int reg = 0; reg < 4; ++reg)
                okr[reg] = okr[reg] && (acc1[n][reg] + b2v[n] < 0.92f);
        #pragma unroll
        for (int reg = 0; reg < 4; ++reg) {
            unsigned long long bal = __ballot(okr[reg]);
            #pragma unroll
            for (int q = 0; q < 4; ++q)
                if (((bal >> (q * 16)) & 0xFFFFULL) == 0xFFFFULL)
                    rowok |= 1u << (16 + q * 4 + reg);
        }
    }

    // closed-form output if s2==0: v3 charges toward b3 (row-independent)
    const float b3v = (lane < ADIM) ? b3[lane] : 0.f;
    float gv;
    {
        float v3 = 0.f, vm = -3.0e38f;
        #pragma unroll
        for (int t = 0; t < TSTEPS; ++t) { v3 += (b3v - v3) * 0.5f; vm = fmaxf(vm, v3); }
        gv = 0.05f * tanhf(vm);
    }

    // write out for OK rows: 32 rows x 17 = 544 elems, coalesced over gi
    #pragma unroll
    for (int it = 0; it < 9; ++it) {
        int gi = it * 64 + lane;
        int r = gi / 17, d = gi - r * 17;
        float g = __shfl(gv, d);           // hoisted out of divergence
        if (r < 32 && ((rowok >> r) & 1u)) {
            size_t o = (size_t)(base + r) * ADIM + d;
            out[o] = fminf(fmaxf(g + action[o], -1.f), 1.f);
        }
    }

    // tier3 (soundness net, never taken in practice): full f32 sim per failed row
    unsigned bad = ~rowok;
    if (bad == 0u) return;  // wave-uniform
    while (bad) {
        int rr = __builtin_ctz(bad); bad &= bad - 1;
        int row = base + rr;
        float x1v[7];
        #pragma unroll
        for (int s = 0; s < 7; ++s) { int col = lane + 64 * s; x1v[s] = (col < H1) ? b1[col] : 0.f; }
        for (int k = 0; k < DIN; ++k) {
            float ik = (k < SDIM) ? state[(size_t)row * SDIM + k] : action[(size_t)row * ADIM + k - SDIM];
            #pragma unroll
            for (int s = 0; s < 7; ++s) {
                int col = lane + 64 * s;
                if (col < H1) x1v[s] += ik * W1[(size_t)k * H1 + col];
            }
        }
        float b2f[5];
        #pragma unroll
        for (int c = 0; c < 5; ++c) { int j = lane + 64 * c; b2f[c] = (j < H2) ? b2[j] : 0.f; }
        float v1[7], v2[5], v3 = 0.f, vmax = -3.0e38f;
        #pragma unroll
        for (int s = 0; s < 7; ++s) v1[s] = 0.f;
        #pragma unroll
        for (int c = 0; c < 5; ++c) v2[c] = 0.f;
        for (int t = 0; t < TSTEPS; ++t) {
            float x2[5];
            #pragma unroll
            for (int c = 0; c < 5; ++c) x2[c] = b2f[c];
            #pragma unroll
            for (int s = 0; s < 7; ++s) {
                float v = v1[s] + (x1v[s] - v1[s]) * 0.5f;
                bool sp = v >= 1.0f;
                v1[s] = sp ? 0.f : v;
                unsigned long long m = __ballot(sp);
                while (m) {
                    int j = __builtin_ctzll(m); m &= m - 1;
                    const float* wr = W2 + (size_t)(s * 64 + j) * H2;
                    #pragma unroll
                    for (int c = 0; c < 5; ++c) {
                        int col = lane + 64 * c;
                        if (col < H2) x2[c] += wr[col];
                    }
                }
            }
            float x3 = b3v;
            #pragma unroll
            for (int c = 0; c < 5; ++c) {
                float v = v2[c] + (x2[c] - v2[c]) * 0.5f;
                int col = lane + 64 * c;
                bool sp = (col < H2) && (v >= 1.0f);
                v2[c] = sp ? 0.f : v;
                unsigned long long m = __ballot(sp);
                while (m) {
                    int j = __builtin_ctzll(m); m &= m - 1;
                    if (lane < ADIM) x3 += W3[(size_t)(c * 64 + j) * ADIM + lane];
                }
            }
            v3 += (x3 - v3) * 0.5f;
            vmax = fmaxf(vmax, v3);
        }
        if (lane < ADIM)
            out[(size_t)row * ADIM + lane] =
                fminf(fmaxf(0.05f * tanhf(vmax) + action[(size_t)row * ADIM + lane], -1.f), 1.f);
    }
}

extern "C" void kernel_launch(void* const* d_in, const int* in_sizes, int n_in,
                              void* d_out, int out_size, void* d_ws, size_t ws_size,
                              hipStream_t stream) {
    const float* state  = (const float*)d_in[0];
    const float* action = (const float*)d_in[1];
    const float* W1     = (const float*)d_in[2];
    const float* b1     = (const float*)d_in[3];
    const float* W2     = (const float*)d_in[4];
    const float* b2     = (const float*)d_in[5];
    const float* W3     = (const float*)d_in[6];
    const float* b3     = (const float*)d_in[7];
    float* out = (float*)d_out;

    const int B = in_sizes[0] / SDIM;  // 8192

    char* p = (char*)d_ws;
    __bf16* A_sw = (__bf16*)p;                 p += (size_t)B * KP * 2;
    __bf16* B_sw = (__bf16*)p;                 p += (size_t)H1 * KP * 2;
    __bf16* B2_sw = (__bf16*)p;                p += (size_t)NT2 * NKT * 64 * 8 * 2;
    unsigned short* maskbuf = (unsigned short*)p;
    unsigned long long* mask64 = (unsigned long long*)p;

    const int npack = (B * 52 + 255) / 256;        // 1664
    const int nw1t  = (H1 * KP + 255) / 256;       // 650
    const int nw2t  = (KP2 * 304 + 255) / 256;     // 494
    prep_fused<<<npack + nw1t + nw2t, 256, 0, stream>>>(state, action, W1, W2,
                                                       A_sw, B_sw, B2_sw, B, npack, nw1t);
    gemm_mask<<<dim3(B / 64, 5), 256, 0, stream>>>(A_sw, B_sw, b1, maskbuf);
    bound_gemm<<<B / 32, 64, 0, stream>>>(mask64, B2_sw, state, action,
                                          W1, b1, W2, b2, W3, b3, out);
}

// Round 2
// 149.824 us; speedup vs baseline: 1.0402x; 1.0402x over previous
//
#include <hip/hip_runtime.h>
#include <math.h>

#define SDIM 376
#define ADIM 17
#define DIN  393
#define H1   400
#define H2   300
#define TSTEPS 32
#define KP 416   // 13*32 (padded DIN)
#define NKT 13   // K tiles of 32
#define NT2 19   // n-tiles for H2 (304 padded cols)
#define KP2 416  // padded H1 (K-dim of bound GEMM)

typedef __bf16 bf16x8 __attribute__((ext_vector_type(8)));
typedef float  f32x4  __attribute__((ext_vector_type(4)));

// Fragment-major layouts: frag for (tile, kt) is 64 lanes x 8 bf16, contiguous:
//   A_sw[((mtile*13 + kt)*64 + lane)*8 + e]   lane = quad*16 + (row&15), e = k&7, quad=(k>>3)&3
//   B_sw[((ntile*13 + kt)*64 + lane)*8 + e]   lane = quad*16 + (col&15)
// => every MFMA fragment load is ONE coalesced 1KB wave transaction.
//
// R1: bound_gemm restructured after R0 post-mortem (69us, 2.6% occupancy, 1% MfmaUtil:
// 494-deep serial load->MFMA chain, 152 VGPRs of dead accumulators).
//   - 512 single-wave blocks (1 m-tile = 16 rows each), 2 waves/CU
//   - n-OUTER / kt-INNER with acc folding: 2 live accs, 13 independent loads/n-tile
//   - n-tiles processed in pairs: 2 independent MFMA dep chains
//   - A-frags (mask bits -> bf16 0/1) built once, reused across all 19 n-tiles

// ---------- K0 (fused prep): input -> A_sw | W1 -> B_sw | W2+ -> B2_sw ----------
__global__ __launch_bounds__(256) void prep_fused(
    const float* __restrict__ state, const float* __restrict__ action,
    const float* __restrict__ W1, const float* __restrict__ W2,
    __bf16* __restrict__ A_sw, __bf16* __restrict__ B_sw, __bf16* __restrict__ B2_sw,
    int B, int npack, int nw1t) {
    const int bid = blockIdx.x, tid = threadIdx.x;
    if (bid < npack) {
        // pack concat(state,action,0): thread -> (row r, 8-col chunk c); source reads coalesced
        int idx = bid * 256 + tid;
        int r = idx / 52, c = idx - r * 52;
        if (r >= B) return;
        int g0 = c * 8;
        float v[8];
        if (g0 + 7 < SDIM) {
            float4 a = *(const float4*)&state[r * SDIM + g0];
            float4 b = *(const float4*)&state[r * SDIM + g0 + 4];
            v[0]=a.x; v[1]=a.y; v[2]=a.z; v[3]=a.w; v[4]=b.x; v[5]=b.y; v[6]=b.z; v[7]=b.w;
        } else {
            #pragma unroll
            for (int e = 0; e < 8; ++e) {
                int k = g0 + e;
                v[e] = (k < SDIM) ? state[r * SDIM + k]
                     : (k < DIN)  ? action[r * ADIM + k - SDIM] : 0.f;
            }
        }
        bf16x8 o;
        #pragma unroll
        for (int e = 0; e < 8; ++e) o[e] = (__bf16)v[e];
        int kt = g0 >> 5, quad = (g0 >> 3) & 3;
        *(bf16x8*)&A_sw[(((size_t)(r >> 4) * NKT + kt) * 64 + (quad << 4) + (r & 15)) * 8] = o;
    } else if (bid < npack + nw1t) {
        // W1 [k][n] -> B_sw, k-major thread mapping => W1 reads fully coalesced
        int idx = (bid - npack) * 256 + tid;
        if (idx >= H1 * KP) return;
        int k = idx / H1, n = idx - k * H1;
        float val = (k < DIN) ? W1[k * H1 + n] : 0.f;
        int ntile = n >> 4, kt = k >> 5, quad = (k >> 3) & 3;
        B_sw[(((size_t)ntile * NKT + kt) * 64 + (quad << 4) + (n & 15)) * 8 + (k & 7)] = (__bf16)val;
    } else {
        // W2+ = max(W2,0) [k2][n2] -> B2_sw frags, k2 in [0,416), n2 in [0,304)
        int idx = (bid - npack - nw1t) * 256 + tid;
        if (idx >= KP2 * 304) return;
        int k = idx / 304, n = idx - k * 304;
        float val = (k < H1 && n < H2) ? fmaxf(W2[k * H2 + n], 0.f) : 0.f;
        int ntile = n >> 4, kt = k >> 5, quad = (k >> 3) & 3;
        B2_sw[(((size_t)ntile * NKT + kt) * 64 + (quad << 4) + (n & 15)) * 8 + (k & 7)] = (__bf16)val;
    }
}

// ---------- K1: GEMM -> spike mask. Unchanged. ----------
__global__ __launch_bounds__(256) void gemm_mask(
    const __bf16* __restrict__ A_sw, const __bf16* __restrict__ B_sw,
    const float* __restrict__ b1, unsigned short* __restrict__ maskbuf) {
    const int tid = threadIdx.x, wave = tid >> 6, lane = tid & 63;
    const int quad = lane >> 4, l16 = lane & 15;
    const int mtile = blockIdx.x * 4 + wave;       // this wave's 16 rows
    const int bn0 = blockIdx.y * 80;               // 5 n-tiles

    f32x4 acc[5];
    #pragma unroll
    for (int n = 0; n < 5; ++n) acc[n] = (f32x4){0.f, 0.f, 0.f, 0.f};

    const __bf16* ap = A_sw + ((size_t)mtile * NKT * 64 + lane) * 8;
    const __bf16* bp = B_sw + ((size_t)(blockIdx.y * 5) * NKT * 64 + lane) * 8;

    #pragma unroll
    for (int kt = 0; kt < NKT; ++kt) {
        bf16x8 af = *(const bf16x8*)(ap + (size_t)kt * 512);
        #pragma unroll
        for (int n = 0; n < 5; ++n) {
            bf16x8 bfrag = *(const bf16x8*)(bp + ((size_t)n * NKT + kt) * 512);
            acc[n] = __builtin_amdgcn_mfma_f32_16x16x32_bf16(af, bfrag, acc[n], 0, 0, 0);
        }
    }

    float b1v[5];
    #pragma unroll
    for (int n = 0; n < 5; ++n) b1v[n] = b1[bn0 + n * 16 + l16];
    const int cbase = bn0 >> 4;  // chunk base = blockIdx.y*5
    const int bm0 = mtile * 16;
    #pragma unroll
    for (int n = 0; n < 5; ++n)
        #pragma unroll
        for (int reg = 0; reg < 4; ++reg) {
            // 0.99: superset of {x1_ref >= 1}; bf16 GEMM |err| << 0.01 at this K/scale
            unsigned long long bal = __ballot(acc[n][reg] + b1v[n] >= 0.99f);
            if (l16 == 0)
                maskbuf[(size_t)(bm0 + quad * 4 + reg) * 32 + cbase + n] =
                    (unsigned short)(bal >> (quad * 16));
        }
}

// ---------- K2': bound GEMM + epilogue. One single-wave block per m-tile (16 rows).
// bound[j] = b2[j] + sum_{i in mask} bf16(max(W2[i][j],0)) via MFMA; if all j:
// bound < 0.92 => s2==0 => closed-form out. (bf16 under-count <= 400*9.8e-5 ~ 0.04;
// 0.92 + 0.04 < 0.999 required => sound.) Tier-3 full sim kept as soundness net. ----------
__global__ __launch_bounds__(64) void bound_gemm(
    const unsigned long long* __restrict__ mask64,   // [B][8] (chunks 25..31 invalid)
    const __bf16* __restrict__ B2_sw,
    const float* __restrict__ state, const float* __restrict__ action,
    const float* __restrict__ W1, const float* __restrict__ b1,
    const float* __restrict__ W2, const float* __restrict__ b2,
    const float* __restrict__ W3, const float* __restrict__ b3,
    float* __restrict__ out) {
    const int lane = threadIdx.x;
    const int l16 = lane & 15, quad = lane >> 4;
    const int base = blockIdx.x * 16;

    // mask words for this lane's row (A-fragment rows = base + l16)
    unsigned long long mw[7];
    #pragma unroll
    for (int w = 0; w < 7; ++w) mw[w] = mask64[(size_t)(base + l16) * 8 + w];
    mw[6] &= 0xFFFFULL;  // chunks 25..27 are unwritten ws

    // build all 13 A-fragments once: k = kt*32 + quad*8 + e
    bf16x8 af[NKT];
    #pragma unroll
    for (int kt = 0; kt < NKT; ++kt) {
        const int bit0 = ((kt & 1) << 5) | (quad << 3);
        unsigned by = (unsigned)(mw[kt >> 1] >> bit0) & 0xFFu;
        #pragma unroll
        for (int e = 0; e < 8; ++e)
            af[kt][e] = ((by >> e) & 1u) ? (__bf16)1.0f : (__bf16)0.0f;
    }

    // preload b2 per n-tile (col j = n*16 + l16)
    float b2v[NT2];
    #pragma unroll
    for (int n = 0; n < NT2; ++n) {
        int j = n * 16 + l16;
        b2v[n] = (j < H2) ? b2[j] : 0.f;
    }

    // n-outer / kt-inner, paired n-tiles for 2 independent MFMA chains.
    const __bf16* bp = B2_sw + (size_t)lane * 8;
    bool okr[4] = {true, true, true, true};
    #pragma unroll
    for (int np = 0; np < 10; ++np) {
        const int n0 = np * 2, n1 = np * 2 + 1;
        f32x4 accA = (f32x4){0.f, 0.f, 0.f, 0.f};
        f32x4 accB = (f32x4){0.f, 0.f, 0.f, 0.f};
        #pragma unroll
        for (int kt = 0; kt < NKT; ++kt) {
            bf16x8 bf0 = *(const bf16x8*)(bp + ((size_t)(n0 * NKT + kt) * 64) * 8);
            accA = __builtin_amdgcn_mfma_f32_16x16x32_bf16(af[kt], bf0, accA, 0, 0, 0);
            if (n1 < NT2) {
                bf16x8 bf1 = *(const bf16x8*)(bp + ((size_t)(n1 * NKT + kt) * 64) * 8);
                accB = __builtin_amdgcn_mfma_f32_16x16x32_bf16(af[kt], bf1, accB, 0, 0, 0);
            }
        }
        #pragma unroll
        for (int reg = 0; reg < 4; ++reg) {
            okr[reg] = okr[reg] && (accA[reg] + b2v[n0] < 0.92f);
            if (n1 < NT2) okr[reg] = okr[reg] && (accB[reg] + b2v[n1] < 0.92f);
        }
    }

    // per-row OK bits (wave-uniform): row = quad*4 + reg, cols l16 within each n
    unsigned rowok = 0;
    #pragma unroll
    for (int reg = 0; reg < 4; ++reg) {
        unsigned long long bal = __ballot(okr[reg]);
        #pragma unroll
        for (int q = 0; q < 4; ++q)
            if (((bal >> (q * 16)) & 0xFFFFULL) == 0xFFFFULL)
                rowok |= 1u << (q * 4 + reg);
    }

    // closed-form output if s2==0: v3 charges toward b3 (row-independent)
    const float b3v = (lane < ADIM) ? b3[lane] : 0.f;
    float gv;
    {
        float v3 = 0.f, vm = -3.0e38f;
        #pragma unroll
        for (int t = 0; t < TSTEPS; ++t) { v3 += (b3v - v3) * 0.5f; vm = fmaxf(vm, v3); }
        gv = 0.05f * tanhf(vm);
    }

    // write out for OK rows: 16 rows x 17 = 272 elems, coalesced over gi
    #pragma unroll
    for (int it = 0; it < 5; ++it) {
        int gi = it * 64 + lane;
        int r = gi / 17, d = gi - r * 17;
        float g = __shfl(gv, d);           // hoisted out of divergence
        if (r < 16 && ((rowok >> r) & 1u)) {
            size_t o = (size_t)(base + r) * ADIM + d;
            out[o] = fminf(fmaxf(g + action[o], -1.f), 1.f);
        }
    }

    // tier3 (soundness net, never taken in practice): full f32 sim per failed row
    unsigned bad = (~rowok) & 0xFFFFu;
    if (bad == 0u) return;  // wave-uniform
    while (bad) {
        int rr = __builtin_ctz(bad); bad &= bad - 1;
        int row = base + rr;
        float x1v[7];
        #pragma unroll
        for (int s = 0; s < 7; ++s) { int col = lane + 64 * s; x1v[s] = (col < H1) ? b1[col] : 0.f; }
        for (int k = 0; k < DIN; ++k) {
            float ik = (k < SDIM) ? state[(size_t)row * SDIM + k] : action[(size_t)row * ADIM + k - SDIM];
            #pragma unroll
            for (int s = 0; s < 7; ++s) {
                int col = lane + 64 * s;
                if (col < H1) x1v[s] += ik * W1[(size_t)k * H1 + col];
            }
        }
        float b2f[5];
        #pragma unroll
        for (int c = 0; c < 5; ++c) { int j = lane + 64 * c; b2f[c] = (j < H2) ? b2[j] : 0.f; }
        float v1[7], v2[5], v3 = 0.f, vmax = -3.0e38f;
        #pragma unroll
        for (int s = 0; s < 7; ++s) v1[s] = 0.f;
        #pragma unroll
        for (int c = 0; c < 5; ++c) v2[c] = 0.f;
        for (int t = 0; t < TSTEPS; ++t) {
            float x2[5];
            #pragma unroll
            for (int c = 0; c < 5; ++c) x2[c] = b2f[c];
            #pragma unroll
            for (int s = 0; s < 7; ++s) {
                float v = v1[s] + (x1v[s] - v1[s]) * 0.5f;
                bool sp = v >= 1.0f;
                v1[s] = sp ? 0.f : v;
                unsigned long long m = __ballot(sp);
                while (m) {
                    int j = __builtin_ctzll(m); m &= m - 1;
                    const float* wr = W2 + (size_t)(s * 64 + j) * H2;
                    #pragma unroll
                    for (int c = 0; c < 5; ++c) {
                        int col = lane + 64 * c;
                        if (col < H2) x2[c] += wr[col];
                    }
                }
            }
            float x3 = b3v;
            #pragma unroll
            for (int c = 0; c < 5; ++c) {
                float v = v2[c] + (x2[c] - v2[c]) * 0.5f;
                int col = lane + 64 * c;
                bool sp = (col < H2) && (v >= 1.0f);
                v2[c] = sp ? 0.f : v;
                unsigned long long m = __ballot(sp);
                while (m) {
                    int j = __builtin_ctzll(m); m &= m - 1;
                    if (lane < ADIM) x3 += W3[(size_t)(c * 64 + j) * ADIM + lane];
                }
            }
            v3 += (x3 - v3) * 0.5f;
            vmax = fmaxf(vmax, v3);
        }
        if (lane < ADIM)
            out[(size_t)row * ADIM + lane] =
                fminf(fmaxf(0.05f * tanhf(vmax) + action[(size_t)row * ADIM + lane], -1.f), 1.f);
    }
}

extern "C" void kernel_launch(void* const* d_in, const int* in_sizes, int n_in,
                              void* d_out, int out_size, void* d_ws, size_t ws_size,
                              hipStream_t stream) {
    const float* state  = (const float*)d_in[0];
    const float* action = (const float*)d_in[1];
    const float* W1     = (const float*)d_in[2];
    const float* b1     = (const float*)d_in[3];
    const float* W2     = (const float*)d_in[4];
    const float* b2     = (const float*)d_in[5];
    const float* W3     = (const float*)d_in[6];
    const float* b3     = (const float*)d_in[7];
    float* out = (float*)d_out;

    const int B = in_sizes[0] / SDIM;  // 8192

    char* p = (char*)d_ws;
    __bf16* A_sw = (__bf16*)p;                 p += (size_t)B * KP * 2;
    __bf16* B_sw = (__bf16*)p;                 p += (size_t)H1 * KP * 2;
    __bf16* B2_sw = (__bf16*)p;                p += (size_t)NT2 * NKT * 64 * 8 * 2;
    unsigned short* maskbuf = (unsigned short*)p;
    unsigned long long* mask64 = (unsigned long long*)p;

    const int npack = (B * 52 + 255) / 256;        // 1664
    const int nw1t  = (H1 * KP + 255) / 256;       // 650
    const int nw2t  = (KP2 * 304 + 255) / 256;     // 494
    prep_fused<<<npack + nw1t + nw2t, 256, 0, stream>>>(state, action, W1, W2,
                                                       A_sw, B_sw, B2_sw, B, npack, nw1t);
    gemm_mask<<<dim3(B / 64, 5), 256, 0, stream>>>(A_sw, B_sw, b1, maskbuf);
    bound_gemm<<<B / 16, 64, 0, stream>>>(mask64, B2_sw, state, action,
                                          W1, b1, W2, b2, W3, b3, out);
}

// Round 3
// 97.183 us; speedup vs baseline: 1.6037x; 1.5417x over previous
//
#include <hip/hip_runtime.h>
#include <math.h>

#define SDIM 376
#define ADIM 17
#define DIN  393
#define H1   400
#define H2   300
#define TSTEPS 32
#define KP 416   // 13*32 (padded DIN)
#define NKT 13   // K tiles of 32
#define NT2 19   // n-tiles for H2 (304 padded cols)
#define KP2 416  // padded H1 (K-dim of bound GEMM)

typedef __bf16 bf16x8 __attribute__((ext_vector_type(8)));
typedef float  f32x4  __attribute__((ext_vector_type(4)));

// Fragment-major layouts: frag for (tile, kt) is 64 lanes x 8 bf16, contiguous:
//   A_sw[((mtile*13 + kt)*64 + lane)*8 + e]   lane = quad*16 + (row&15), e = k&7, quad=(k>>3)&3
//   B_sw[((ntile*13 + kt)*64 + lane)*8 + e]   lane = quad*16 + (col&15)
// => every MFMA fragment load is ONE coalesced 1KB wave transaction.
//
// R2: bound_gemm restructured after R1 post-mortem (63us, occupancy 5.3% = 2 waves/CU,
// VGPR capped at 84 by launch_bounds(64) -> zero load overlap, ~580cy/load serial).
//   - 512 blocks x 4 waves = 8 waves/CU (mirrors gemm_mask's proven shape)
//   - wave w owns n-tiles {w, w+4, ...}: 65 MFMAs/wave, not 247
//   - launch_bounds(256,2): VGPR cap 256 -> room for 13-frag prefetch queue
//   - explicit cur/nxt double-buffer: next tile's 13 loads issued before current MFMA chain
//   - per-wave rowok combined via LDS + syncthreads; wave 0 writes out / tier3

// ---------- K0 (fused prep): input -> A_sw | W1 -> B_sw | W2+ -> B2_sw ----------
__global__ __launch_bounds__(256) void prep_fused(
    const float* __restrict__ state, const float* __restrict__ action,
    const float* __restrict__ W1, const float* __restrict__ W2,
    __bf16* __restrict__ A_sw, __bf16* __restrict__ B_sw, __bf16* __restrict__ B2_sw,
    int B, int npack, int nw1t) {
    const int bid = blockIdx.x, tid = threadIdx.x;
    if (bid < npack) {
        // pack concat(state,action,0): thread -> (row r, 8-col chunk c); source reads coalesced
        int idx = bid * 256 + tid;
        int r = idx / 52, c = idx - r * 52;
        if (r >= B) return;
        int g0 = c * 8;
        float v[8];
        if (g0 + 7 < SDIM) {
            float4 a = *(const float4*)&state[r * SDIM + g0];
            float4 b = *(const float4*)&state[r * SDIM + g0 + 4];
            v[0]=a.x; v[1]=a.y; v[2]=a.z; v[3]=a.w; v[4]=b.x; v[5]=b.y; v[6]=b.z; v[7]=b.w;
        } else {
            #pragma unroll
            for (int e = 0; e < 8; ++e) {
                int k = g0 + e;
                v[e] = (k < SDIM) ? state[r * SDIM + k]
                     : (k < DIN)  ? action[r * ADIM + k - SDIM] : 0.f;
            }
        }
        bf16x8 o;
        #pragma unroll
        for (int e = 0; e < 8; ++e) o[e] = (__bf16)v[e];
        int kt = g0 >> 5, quad = (g0 >> 3) & 3;
        *(bf16x8*)&A_sw[(((size_t)(r >> 4) * NKT + kt) * 64 + (quad << 4) + (r & 15)) * 8] = o;
    } else if (bid < npack + nw1t) {
        // W1 [k][n] -> B_sw, k-major thread mapping => W1 reads fully coalesced
        int idx = (bid - npack) * 256 + tid;
        if (idx >= H1 * KP) return;
        int k = idx / H1, n = idx - k * H1;
        float val = (k < DIN) ? W1[k * H1 + n] : 0.f;
        int ntile = n >> 4, kt = k >> 5, quad = (k >> 3) & 3;
        B_sw[(((size_t)ntile * NKT + kt) * 64 + (quad << 4) + (n & 15)) * 8 + (k & 7)] = (__bf16)val;
    } else {
        // W2+ = max(W2,0) [k2][n2] -> B2_sw frags, k2 in [0,416), n2 in [0,304)
        int idx = (bid - npack - nw1t) * 256 + tid;
        if (idx >= KP2 * 304) return;
        int k = idx / 304, n = idx - k * 304;
        float val = (k < H1 && n < H2) ? fmaxf(W2[k * H2 + n], 0.f) : 0.f;
        int ntile = n >> 4, kt = k >> 5, quad = (k >> 3) & 3;
        B2_sw[(((size_t)ntile * NKT + kt) * 64 + (quad << 4) + (n & 15)) * 8 + (k & 7)] = (__bf16)val;
    }
}

// ---------- K1: GEMM -> spike mask. Unchanged. ----------
__global__ __launch_bounds__(256) void gemm_mask(
    const __bf16* __restrict__ A_sw, const __bf16* __restrict__ B_sw,
    const float* __restrict__ b1, unsigned short* __restrict__ maskbuf) {
    const int tid = threadIdx.x, wave = tid >> 6, lane = tid & 63;
    const int quad = lane >> 4, l16 = lane & 15;
    const int mtile = blockIdx.x * 4 + wave;       // this wave's 16 rows
    const int bn0 = blockIdx.y * 80;               // 5 n-tiles

    f32x4 acc[5];
    #pragma unroll
    for (int n = 0; n < 5; ++n) acc[n] = (f32x4){0.f, 0.f, 0.f, 0.f};

    const __bf16* ap = A_sw + ((size_t)mtile * NKT * 64 + lane) * 8;
    const __bf16* bp = B_sw + ((size_t)(blockIdx.y * 5) * NKT * 64 + lane) * 8;

    #pragma unroll
    for (int kt = 0; kt < NKT; ++kt) {
        bf16x8 af = *(const bf16x8*)(ap + (size_t)kt * 512);
        #pragma unroll
        for (int n = 0; n < 5; ++n) {
            bf16x8 bfrag = *(const bf16x8*)(bp + ((size_t)n * NKT + kt) * 512);
            acc[n] = __builtin_amdgcn_mfma_f32_16x16x32_bf16(af, bfrag, acc[n], 0, 0, 0);
        }
    }

    float b1v[5];
    #pragma unroll
    for (int n = 0; n < 5; ++n) b1v[n] = b1[bn0 + n * 16 + l16];
    const int cbase = bn0 >> 4;  // chunk base = blockIdx.y*5
    const int bm0 = mtile * 16;
    #pragma unroll
    for (int n = 0; n < 5; ++n)
        #pragma unroll
        for (int reg = 0; reg < 4; ++reg) {
            // 0.99: superset of {x1_ref >= 1}; bf16 GEMM |err| << 0.01 at this K/scale
            unsigned long long bal = __ballot(acc[n][reg] + b1v[n] >= 0.99f);
            if (l16 == 0)
                maskbuf[(size_t)(bm0 + quad * 4 + reg) * 32 + cbase + n] =
                    (unsigned short)(bal >> (quad * 16));
        }
}

// ---------- K2': bound GEMM + epilogue. 512 blocks x 4 waves; wave w owns n-tiles
// {w, w+4, ...}. bound[j] = b2[j] + sum_{i in mask} bf16(max(W2[i][j],0)) via MFMA;
// if all j: bound < 0.92 => s2==0 => closed-form out. (bf16 under-count <= ~0.04;
// 0.92+0.04 < 0.999 => sound.) Tier-3 full sim kept as soundness net. ----------
__global__ __launch_bounds__(256, 2) void bound_gemm(
    const unsigned long long* __restrict__ mask64,   // [B][8] (chunks 25..31 invalid)
    const __bf16* __restrict__ B2_sw,
    const float* __restrict__ state, const float* __restrict__ action,
    const float* __restrict__ W1, const float* __restrict__ b1,
    const float* __restrict__ W2, const float* __restrict__ b2,
    const float* __restrict__ W3, const float* __restrict__ b3,
    float* __restrict__ out) {
    const int tid = threadIdx.x;
    const int lane = tid & 63, w = tid >> 6;
    const int l16 = lane & 15, quad = lane >> 4;
    const int base = blockIdx.x * 16;
    __shared__ unsigned s_ok[4];

    // mask words for this lane's row (A-fragment rows = base + l16); same for all 4 waves
    unsigned long long mw[7];
    #pragma unroll
    for (int i = 0; i < 7; ++i) mw[i] = mask64[(size_t)(base + l16) * 8 + i];
    mw[6] &= 0xFFFFULL;  // chunks 25..27 are unwritten ws

    // build all 13 A-fragments once: k = kt*32 + quad*8 + e
    bf16x8 af[NKT];
    #pragma unroll
    for (int kt = 0; kt < NKT; ++kt) {
        const int bit0 = ((kt & 1) << 5) | (quad << 3);
        unsigned by = (unsigned)(mw[kt >> 1] >> bit0) & 0xFFu;
        #pragma unroll
        for (int e = 0; e < 8; ++e)
            af[kt][e] = ((by >> e) & 1u) ? (__bf16)1.0f : (__bf16)0.0f;
    }

    // b2 per owned n-tile (tile i -> n = w + 4*i, col j = n*16 + l16)
    float b2v[5];
    #pragma unroll
    for (int i = 0; i < 5; ++i) {
        int n = w + 4 * i;
        int j = n * 16 + l16;
        b2v[i] = (n < NT2 && j < H2) ? b2[j] : 0.f;
    }

    const __bf16* bp = B2_sw + (size_t)lane * 8;
    bool okr[4] = {true, true, true, true};

    // software-pipelined over this wave's n-tiles: prefetch i+1 before i's MFMA chain
    bf16x8 cur[NKT], nxt[NKT];
    {
        const __bf16* t0 = bp + ((size_t)w * NKT) * 512;
        #pragma unroll
        for (int kt = 0; kt < NKT; ++kt) cur[kt] = *(const bf16x8*)(t0 + (size_t)kt * 512);
    }
    #pragma unroll
    for (int i = 0; i < 5; ++i) {
        const int n = w + 4 * i;
        if (n < NT2) {
            const int nn = w + 4 * (i + 1);
            if (i < 4 && nn < NT2) {
                const __bf16* tn = bp + ((size_t)nn * NKT) * 512;
                #pragma unroll
                for (int kt = 0; kt < NKT; ++kt) nxt[kt] = *(const bf16x8*)(tn + (size_t)kt * 512);
            }
            f32x4 acc = (f32x4){0.f, 0.f, 0.f, 0.f};
            #pragma unroll
            for (int kt = 0; kt < NKT; ++kt)
                acc = __builtin_amdgcn_mfma_f32_16x16x32_bf16(af[kt], cur[kt], acc, 0, 0, 0);
            #pragma unroll
            for (int reg = 0; reg < 4; ++reg)
                okr[reg] = okr[reg] && (acc[reg] + b2v[i] < 0.92f);
            #pragma unroll
            for (int kt = 0; kt < NKT; ++kt) cur[kt] = nxt[kt];
        }
    }

    // per-row OK bits (wave-uniform): row = quad*4 + reg
    unsigned rowok_w = 0;
    #pragma unroll
    for (int reg = 0; reg < 4; ++reg) {
        unsigned long long bal = __ballot(okr[reg]);
        #pragma unroll
        for (int q = 0; q < 4; ++q)
            if (((bal >> (q * 16)) & 0xFFFFULL) == 0xFFFFULL)
                rowok_w |= 1u << (q * 4 + reg);
    }
    if (lane == 0) s_ok[w] = rowok_w;
    __syncthreads();
    const unsigned rowok = s_ok[0] & s_ok[1] & s_ok[2] & s_ok[3];
    if (w != 0) return;   // waves 1..3 done; wave 0 writes output / tier3

    // closed-form output if s2==0: v3 charges toward b3 (row-independent)
    const float b3v = (lane < ADIM) ? b3[lane] : 0.f;
    float gv;
    {
        float v3 = 0.f, vm = -3.0e38f;
        #pragma unroll
        for (int t = 0; t < TSTEPS; ++t) { v3 += (b3v - v3) * 0.5f; vm = fmaxf(vm, v3); }
        gv = 0.05f * tanhf(vm);
    }

    // write out for OK rows: 16 rows x 17 = 272 elems, coalesced over gi
    #pragma unroll
    for (int it = 0; it < 5; ++it) {
        int gi = it * 64 + lane;
        int r = gi / 17, d = gi - r * 17;
        float g = __shfl(gv, d);           // hoisted out of divergence
        if (r < 16 && ((rowok >> r) & 1u)) {
            size_t o = (size_t)(base + r) * ADIM + d;
            out[o] = fminf(fmaxf(g + action[o], -1.f), 1.f);
        }
    }

    // tier3 (soundness net, never taken in practice): full f32 sim per failed row
    unsigned bad = (~rowok) & 0xFFFFu;
    if (bad == 0u) return;  // wave-uniform
    while (bad) {
        int rr = __builtin_ctz(bad); bad &= bad - 1;
        int row = base + rr;
        float x1v[7];
        #pragma unroll
        for (int s = 0; s < 7; ++s) { int col = lane + 64 * s; x1v[s] = (col < H1) ? b1[col] : 0.f; }
        for (int k = 0; k < DIN; ++k) {
            float ik = (k < SDIM) ? state[(size_t)row * SDIM + k] : action[(size_t)row * ADIM + k - SDIM];
            #pragma unroll
            for (int s = 0; s < 7; ++s) {
                int col = lane + 64 * s;
                if (col < H1) x1v[s] += ik * W1[(size_t)k * H1 + col];
            }
        }
        float b2f[5];
        #pragma unroll
        for (int c = 0; c < 5; ++c) { int j = lane + 64 * c; b2f[c] = (j < H2) ? b2[j] : 0.f; }
        float v1[7], v2[5], v3 = 0.f, vmax = -3.0e38f;
        #pragma unroll
        for (int s = 0; s < 7; ++s) v1[s] = 0.f;
        #pragma unroll
        for (int c = 0; c < 5; ++c) v2[c] = 0.f;
        for (int t = 0; t < TSTEPS; ++t) {
            float x2[5];
            #pragma unroll
            for (int c = 0; c < 5; ++c) x2[c] = b2f[c];
            #pragma unroll
            for (int s = 0; s < 7; ++s) {
                float v = v1[s] + (x1v[s] - v1[s]) * 0.5f;
                bool sp = v >= 1.0f;
                v1[s] = sp ? 0.f : v;
                unsigned long long m = __ballot(sp);
                while (m) {
                    int j = __builtin_ctzll(m); m &= m - 1;
                    const float* wr = W2 + (size_t)(s * 64 + j) * H2;
                    #pragma unroll
                    for (int c = 0; c < 5; ++c) {
                        int col = lane + 64 * c;
                        if (col < H2) x2[c] += wr[col];
                    }
                }
            }
            float x3 = b3v;
            #pragma unroll
            for (int c = 0; c < 5; ++c) {
                float v = v2[c] + (x2[c] - v2[c]) * 0.5f;
                int col = lane + 64 * c;
                bool sp = (col < H2) && (v >= 1.0f);
                v2[c] = sp ? 0.f : v;
                unsigned long long m = __ballot(sp);
                while (m) {
                    int j = __builtin_ctzll(m); m &= m - 1;
                    if (lane < ADIM) x3 += W3[(size_t)(c * 64 + j) * ADIM + lane];
                }
            }
            v3 += (x3 - v3) * 0.5f;
            vmax = fmaxf(vmax, v3);
        }
        if (lane < ADIM)
            out[(size_t)row * ADIM + lane] =
                fminf(fmaxf(0.05f * tanhf(vmax) + action[(size_t)row * ADIM + lane], -1.f), 1.f);
    }
}

extern "C" void kernel_launch(void* const* d_in, const int* in_sizes, int n_in,
                              void* d_out, int out_size, void* d_ws, size_t ws_size,
                              hipStream_t stream) {
    const float* state  = (const float*)d_in[0];
    const float* action = (const float*)d_in[1];
    const float* W1     = (const float*)d_in[2];
    const float* b1     = (const float*)d_in[3];
    const float* W2     = (const float*)d_in[4];
    const float* b2     = (const float*)d_in[5];
    const float* W3     = (const float*)d_in[6];
    const float* b3     = (const float*)d_in[7];
    float* out = (float*)d_out;

    const int B = in_sizes[0] / SDIM;  // 8192

    char* p = (char*)d_ws;
    __bf16* A_sw = (__bf16*)p;                 p += (size_t)B * KP * 2;
    __bf16* B_sw = (__bf16*)p;                 p += (size_t)H1 * KP * 2;
    __bf16* B2_sw = (__bf16*)p;                p += (size_t)NT2 * NKT * 64 * 8 * 2;
    unsigned short* maskbuf = (unsigned short*)p;
    unsigned long long* mask64 = (unsigned long long*)p;

    const int npack = (B * 52 + 255) / 256;        // 1664
    const int nw1t  = (H1 * KP + 255) / 256;       // 650
    const int nw2t  = (KP2 * 304 + 255) / 256;     // 494
    prep_fused<<<npack + nw1t + nw2t, 256, 0, stream>>>(state, action, W1, W2,
                                                       A_sw, B_sw, B2_sw, B, npack, nw1t);
    gemm_mask<<<dim3(B / 64, 5), 256, 0, stream>>>(A_sw, B_sw, b1, maskbuf);
    bound_gemm<<<B / 16, 256, 0, stream>>>(mask64, B2_sw, state, action,
                                           W1, b1, W2, b2, W3, b3, out);
}

// Round 4
// 92.515 us; speedup vs baseline: 1.6846x; 1.0505x over previous
//
#include <hip/hip_runtime.h>
#include <math.h>

#define SDIM 376
#define ADIM 17
#define DIN  393
#define H1   400
#define H2   300
#define TSTEPS 32
#define KP 416   // 13*32 (padded DIN / padded H1 as K-dims)
#define NKT 13   // K tiles of 32
#define NT1 25   // n-tiles for H1 (400 cols, exact)
#define NT2 19   // n-tiles for H2 (304 padded cols)
#define LDA 424  // a_lds row stride in bf16 (pad 416+8: breaks 16-row bank aliasing)

typedef __bf16 bf16x8 __attribute__((ext_vector_type(8)));
typedef float  f32x4  __attribute__((ext_vector_type(4)));

// R3: fuse gemm_mask + bound_gemm into one kernel (mask lives in LDS; bound block
// needs only its own 32 rows' masks). Input A-pack moves into the fused kernel's
// prologue (state -> LDS bf16 frags) -- A_sw and maskbuf eliminated from global ws.
// Structure per block (256 thr = 4 waves, 32 rows, 8 waves/CU):
//   pack 32x416 bf16 rows into a_lds -> barrier
//   phase1: wave (m=w&1, h=w>>1) computes layer-1 GEMM for mtile m, ntiles {h,h+2,..}<25
//           (13-frag double-buffer, chain order identical to R2's gemm_mask);
//           ballots -> s_mask[row][chunk] in LDS
//   barrier
//   phase2: af rebuilt from s_mask; bound GEMM over H2 ntiles {h,h+2,..}<19
//           (identical R2 double-buffer); rowok per wave -> s_ok
//   barrier; rowok(m) = s_ok[m] & s_ok[m+2]; waves 0,1 write out / tier3 for their mtile.
// Thresholds unchanged: mask 0.99 (superset of x1>=1), bound 0.92 (bf16 undercount <=~0.04).

// ---------- K0: weights only. W1 -> B_sw | W2+ -> B2_sw ----------
__global__ __launch_bounds__(256) void prep_w(
    const float* __restrict__ W1, const float* __restrict__ W2,
    __bf16* __restrict__ B_sw, __bf16* __restrict__ B2_sw, int nw1t) {
    const int bid = blockIdx.x, tid = threadIdx.x;
    if (bid < nw1t) {
        // W1 [k][n] -> B_sw, k-major thread mapping => W1 reads fully coalesced
        int idx = bid * 256 + tid;
        if (idx >= H1 * KP) return;
        int k = idx / H1, n = idx - k * H1;
        float val = (k < DIN) ? W1[k * H1 + n] : 0.f;
        int ntile = n >> 4, kt = k >> 5, quad = (k >> 3) & 3;
        B_sw[(((size_t)ntile * NKT + kt) * 64 + (quad << 4) + (n & 15)) * 8 + (k & 7)] = (__bf16)val;
    } else {
        // W2+ = max(W2,0) [k2][n2] -> B2_sw frags, k2 in [0,416), n2 in [0,304)
        int idx = (bid - nw1t) * 256 + tid;
        if (idx >= KP * 304) return;
        int k = idx / 304, n = idx - k * 304;
        float val = (k < H1 && n < H2) ? fmaxf(W2[k * H2 + n], 0.f) : 0.f;
        int ntile = n >> 4, kt = k >> 5, quad = (k >> 3) & 3;
        B2_sw[(((size_t)ntile * NKT + kt) * 64 + (quad << 4) + (n & 15)) * 8 + (k & 7)] = (__bf16)val;
    }
}

// ---------- K1 (fused): pack -> layer-1 mask -> bound GEMM -> epilogue ----------
__global__ __launch_bounds__(256, 2) void mask_bound(
    const __bf16* __restrict__ B_sw, const __bf16* __restrict__ B2_sw,
    const float* __restrict__ state, const float* __restrict__ action,
    const float* __restrict__ W1, const float* __restrict__ b1,
    const float* __restrict__ W2, const float* __restrict__ b2,
    const float* __restrict__ W3, const float* __restrict__ b3,
    float* __restrict__ out) {
    const int tid = threadIdx.x;
    const int lane = tid & 63, w = tid >> 6;
    const int l16 = lane & 15, quad = lane >> 4;
    const int m = w & 1, h = w >> 1;
    const int base = blockIdx.x * 32;

    __shared__ __align__(16) __bf16 a_lds[32][LDA];            // 27136 B
    __shared__ __align__(16) unsigned short s_mask[32][32];    // 2048 B
    __shared__ unsigned s_ok[4];

    // zero mask chunks 25..31 (pad chunks must read as no-spike)
    if ((tid & 7) < 7) s_mask[tid >> 3][25 + (tid & 7)] = 0;

    // ---- pack rows [base, base+32) -> a_lds (bf16 concat(state,action,0)) ----
    #pragma unroll
    for (int it = 0; it < 7; ++it) {
        int u = it * 256 + tid;
        if (u < 32 * 52) {
            int r = u / 52, cc = u - r * 52, g0 = cc * 8;
            const int grow = base + r;
            float v[8];
            if (g0 + 7 < SDIM) {
                float4 a = *(const float4*)&state[(size_t)grow * SDIM + g0];
                float4 b = *(const float4*)&state[(size_t)grow * SDIM + g0 + 4];
                v[0]=a.x; v[1]=a.y; v[2]=a.z; v[3]=a.w; v[4]=b.x; v[5]=b.y; v[6]=b.z; v[7]=b.w;
            } else {
                #pragma unroll
                for (int e = 0; e < 8; ++e) {
                    int k = g0 + e;
                    v[e] = (k < SDIM) ? state[(size_t)grow * SDIM + k]
                         : (k < DIN)  ? action[(size_t)grow * ADIM + k - SDIM] : 0.f;
                }
            }
            bf16x8 o;
            #pragma unroll
            for (int e = 0; e < 8; ++e) o[e] = (__bf16)v[e];
            *(bf16x8*)&a_lds[r][g0] = o;
        }
    }
    __syncthreads();

    // ---- phase 1: layer-1 GEMM -> spike mask in LDS ----
    bf16x8 af[NKT];
    #pragma unroll
    for (int kt = 0; kt < NKT; ++kt)
        af[kt] = *(const bf16x8*)&a_lds[m * 16 + l16][kt * 32 + quad * 8];

    {
        const __bf16* bp = B_sw + (size_t)lane * 8;
        float b1v[13];
        #pragma unroll
        for (int i = 0; i < 13; ++i) {
            int nt = 2 * i + h;
            b1v[i] = (nt < NT1) ? b1[nt * 16 + l16] : 0.f;
        }
        bf16x8 cur[NKT], nxt[NKT];
        {
            const __bf16* t0 = bp + (size_t)h * NKT * 512;
            #pragma unroll
            for (int kt = 0; kt < NKT; ++kt) cur[kt] = *(const bf16x8*)(t0 + (size_t)kt * 512);
        }
        #pragma unroll
        for (int i = 0; i < 13; ++i) {
            const int nt = 2 * i + h;
            if (nt < NT1) {
                const int nn = nt + 2;
                if (nn < NT1) {
                    const __bf16* tn = bp + (size_t)nn * NKT * 512;
                    #pragma unroll
                    for (int kt = 0; kt < NKT; ++kt) nxt[kt] = *(const bf16x8*)(tn + (size_t)kt * 512);
                }
                f32x4 acc = (f32x4){0.f, 0.f, 0.f, 0.f};
                #pragma unroll
                for (int kt = 0; kt < NKT; ++kt)
                    acc = __builtin_amdgcn_mfma_f32_16x16x32_bf16(af[kt], cur[kt], acc, 0, 0, 0);
                #pragma unroll
                for (int reg = 0; reg < 4; ++reg) {
                    // 0.99: superset of {x1_ref >= 1}; bf16 GEMM |err| << 0.01 at this K/scale
                    unsigned long long bal = __ballot(acc[reg] + b1v[i] >= 0.99f);
                    if (l16 == 0)
                        s_mask[m * 16 + quad * 4 + reg][nt] = (unsigned short)(bal >> (quad * 16));
                }
                #pragma unroll
                for (int kt = 0; kt < NKT; ++kt) cur[kt] = nxt[kt];
            }
        }
    }
    __syncthreads();

    // ---- phase 2: bound GEMM. bound[j] = b2[j] + sum_{i in mask} bf16(W2+[i][j]) ----
    {
        unsigned long long mw[7];
        const unsigned long long* mrow = (const unsigned long long*)&s_mask[m * 16 + l16][0];
        #pragma unroll
        for (int i = 0; i < 7; ++i) mw[i] = mrow[i];
        #pragma unroll
        for (int kt = 0; kt < NKT; ++kt) {
            const int bit0 = ((kt & 1) << 5) | (quad << 3);
            unsigned by = (unsigned)(mw[kt >> 1] >> bit0) & 0xFFu;
            #pragma unroll
            for (int e = 0; e < 8; ++e)
                af[kt][e] = ((by >> e) & 1u) ? (__bf16)1.0f : (__bf16)0.0f;
        }

        float b2v[10];
        #pragma unroll
        for (int i = 0; i < 10; ++i) {
            int nt = 2 * i + h;
            int j = nt * 16 + l16;
            b2v[i] = (nt < NT2 && j < H2) ? b2[j] : 0.f;
        }

        const __bf16* bp = B2_sw + (size_t)lane * 8;
        bool okr[4] = {true, true, true, true};
        bf16x8 cur[NKT], nxt[NKT];
        {
            const __bf16* t0 = bp + (size_t)h * NKT * 512;
            #pragma unroll
            for (int kt = 0; kt < NKT; ++kt) cur[kt] = *(const bf16x8*)(t0 + (size_t)kt * 512);
        }
        #pragma unroll
        for (int i = 0; i < 10; ++i) {
            const int nt = 2 * i + h;
            if (nt < NT2) {
                const int nn = nt + 2;
                if (nn < NT2) {
                    const __bf16* tn = bp + (size_t)nn * NKT * 512;
                    #pragma unroll
                    for (int kt = 0; kt < NKT; ++kt) nxt[kt] = *(const bf16x8*)(tn + (size_t)kt * 512);
                }
                f32x4 acc = (f32x4){0.f, 0.f, 0.f, 0.f};
                #pragma unroll
                for (int kt = 0; kt < NKT; ++kt)
                    acc = __builtin_amdgcn_mfma_f32_16x16x32_bf16(af[kt], cur[kt], acc, 0, 0, 0);
                #pragma unroll
                for (int reg = 0; reg < 4; ++reg)
                    okr[reg] = okr[reg] && (acc[reg] + b2v[i] < 0.92f);
                #pragma unroll
                for (int kt = 0; kt < NKT; ++kt) cur[kt] = nxt[kt];
            }
        }

        unsigned rowok_w = 0;
        #pragma unroll
        for (int reg = 0; reg < 4; ++reg) {
            unsigned long long bal = __ballot(okr[reg]);
            #pragma unroll
            for (int q = 0; q < 4; ++q)
                if (((bal >> (q * 16)) & 0xFFFFULL) == 0xFFFFULL)
                    rowok_w |= 1u << (q * 4 + reg);
        }
        if (lane == 0) s_ok[w] = rowok_w;
    }
    __syncthreads();
    const unsigned rowok = s_ok[m] & s_ok[m + 2];
    if (w >= 2) return;   // waves 2,3 done; wave m handles output/tier3 for mtile m
    const int rowbase = base + m * 16;

    // closed-form output if s2==0: v3 charges toward b3 (row-independent)
    const float b3v = (lane < ADIM) ? b3[lane] : 0.f;
    float gv;
    {
        float v3 = 0.f, vm = -3.0e38f;
        #pragma unroll
        for (int t = 0; t < TSTEPS; ++t) { v3 += (b3v - v3) * 0.5f; vm = fmaxf(vm, v3); }
        gv = 0.05f * tanhf(vm);
    }

    // write out for OK rows: 16 rows x 17 = 272 elems, coalesced over gi
    #pragma unroll
    for (int it = 0; it < 5; ++it) {
        int gi = it * 64 + lane;
        int r = gi / 17, d = gi - r * 17;
        float g = __shfl(gv, d);           // hoisted out of divergence
        if (r < 16 && ((rowok >> r) & 1u)) {
            size_t o = (size_t)(rowbase + r) * ADIM + d;
            out[o] = fminf(fmaxf(g + action[o], -1.f), 1.f);
        }
    }

    // tier3 (soundness net, never taken in practice): full f32 sim per failed row
    unsigned bad = (~rowok) & 0xFFFFu;
    if (bad == 0u) return;  // wave-uniform
    while (bad) {
        int rr = __builtin_ctz(bad); bad &= bad - 1;
        int row = rowbase + rr;
        float x1v[7];
        #pragma unroll
        for (int s = 0; s < 7; ++s) { int col = lane + 64 * s; x1v[s] = (col < H1) ? b1[col] : 0.f; }
        for (int k = 0; k < DIN; ++k) {
            float ik = (k < SDIM) ? state[(size_t)row * SDIM + k] : action[(size_t)row * ADIM + k - SDIM];
            #pragma unroll
            for (int s = 0; s < 7; ++s) {
                int col = lane + 64 * s;
                if (col < H1) x1v[s] += ik * W1[(size_t)k * H1 + col];
            }
        }
        float b2f[5];
        #pragma unroll
        for (int c = 0; c < 5; ++c) { int j = lane + 64 * c; b2f[c] = (j < H2) ? b2[j] : 0.f; }
        float v1[7], v2[5], v3 = 0.f, vmax = -3.0e38f;
        #pragma unroll
        for (int s = 0; s < 7; ++s) v1[s] = 0.f;
        #pragma unroll
        for (int c = 0; c < 5; ++c) v2[c] = 0.f;
        for (int t = 0; t < TSTEPS; ++t) {
            float x2[5];
            #pragma unroll
            for (int c = 0; c < 5; ++c) x2[c] = b2f[c];
            #pragma unroll
            for (int s = 0; s < 7; ++s) {
                float v = v1[s] + (x1v[s] - v1[s]) * 0.5f;
                bool sp = v >= 1.0f;
                v1[s] = sp ? 0.f : v;
                unsigned long long mm = __ballot(sp);
                while (mm) {
                    int j = __builtin_ctzll(mm); mm &= mm - 1;
                    const float* wr = W2 + (size_t)(s * 64 + j) * H2;
                    #pragma unroll
                    for (int c = 0; c < 5; ++c) {
                        int col = lane + 64 * c;
                        if (col < H2) x2[c] += wr[col];
                    }
                }
            }
            float x3 = b3v;
            #pragma unroll
            for (int c = 0; c < 5; ++c) {
                float v = v2[c] + (x2[c] - v2[c]) * 0.5f;
                int col = lane + 64 * c;
                bool sp = (col < H2) && (v >= 1.0f);
                v2[c] = sp ? 0.f : v;
                unsigned long long mm = __ballot(sp);
                while (mm) {
                    int j = __builtin_ctzll(mm); mm &= mm - 1;
                    if (lane < ADIM) x3 += W3[(size_t)(c * 64 + j) * ADIM + lane];
                }
            }
            v3 += (x3 - v3) * 0.5f;
            vmax = fmaxf(vmax, v3);
        }
        if (lane < ADIM)
            out[(size_t)row * ADIM + lane] =
                fminf(fmaxf(0.05f * tanhf(vmax) + action[(size_t)row * ADIM + lane], -1.f), 1.f);
    }
}

extern "C" void kernel_launch(void* const* d_in, const int* in_sizes, int n_in,
                              void* d_out, int out_size, void* d_ws, size_t ws_size,
                              hipStream_t stream) {
    const float* state  = (const float*)d_in[0];
    const float* action = (const float*)d_in[1];
    const float* W1     = (const float*)d_in[2];
    const float* b1     = (const float*)d_in[3];
    const float* W2     = (const float*)d_in[4];
    const float* b2     = (const float*)d_in[5];
    const float* W3     = (const float*)d_in[6];
    const float* b3     = (const float*)d_in[7];
    float* out = (float*)d_out;

    const int B = in_sizes[0] / SDIM;  // 8192

    char* p = (char*)d_ws;
    __bf16* B_sw = (__bf16*)p;                 p += (size_t)H1 * KP * 2;
    __bf16* B2_sw = (__bf16*)p;                p += (size_t)NT2 * NKT * 64 * 8 * 2;

    const int nw1t = (H1 * KP + 255) / 256;    // 650
    const int nw2t = (KP * 304 + 255) / 256;   // 494
    prep_w<<<nw1t + nw2t, 256, 0, stream>>>(W1, W2, B_sw, B2_sw, nw1t);
    mask_bound<<<B / 32, 256, 0, stream>>>(B_sw, B2_sw, state, action,
                                           W1, b1, W2, b2, W3, b3, out);
}